// Round 1
// baseline (779.765 us; speedup 1.0000x reference)
//
#include <hip/hip_runtime.h>

// GRU fused kernel: B=2048, T=1024, D=6, H=48.
// Block = 192 threads = 4 batches x 48 hidden units. Thread owns the 3 gate
// rows of W_hh in registers (144 VGPRs); h kept in an 8-deep LDS window
// (broadcast reads); input projection and output FC fused (no gi / hidden
// trajectory ever hits HBM).

namespace {

constexpr int T = 1024;
constexpr int D = 6;
constexpr int H = 48;
constexpr int NB = 4;              // batches per block
constexpr int BLOCK = NB * H;      // 192 threads (3 waves)
constexpr int W = 8;               // h-history window for fused FC
constexpr int HP = 52;             // padded LDS stride (52*4B: 16B-aligned rows, bank-spread)

__device__ __forceinline__ float fexp2(float x) { return __builtin_amdgcn_exp2f(x); }
__device__ __forceinline__ float frcp(float x) { return __builtin_amdgcn_rcpf(x); }
// sigmoid(x) = 1/(1+2^(-x*log2e))
__device__ __forceinline__ float sigmoid_f(float x) {
  return frcp(1.0f + fexp2(-1.44269504088896340736f * x));
}
// tanh(x) = 1 - 2/(2^(2x*log2e)+1); saturates correctly at +/-inf
__device__ __forceinline__ float tanh_f(float x) {
  float e = fexp2(2.88539008177792681472f * x);
  return 1.0f - 2.0f * frcp(e + 1.0f);
}

__global__ __launch_bounds__(BLOCK, 2) void gru_fused(
    const float* __restrict__ x, const float* __restrict__ W_ih,
    const float* __restrict__ W_hh, const float* __restrict__ b_ih,
    const float* __restrict__ b_hh, const float* __restrict__ fc_w,
    const float* __restrict__ fc_b, float* __restrict__ y) {

  __shared__ float h_hist[W][NB][HP];
  __shared__ float fcw_s[D][H];

  const int tid = threadIdx.x;
  const int bl  = tid / H;          // local batch 0..3
  const int u   = tid - bl * H;     // hidden unit 0..47

  // zero h window (h0 = 0; step 0 reads slot W-1), stage fc_w
  for (int i = tid; i < W * NB * HP; i += BLOCK) (&h_hist[0][0][0])[i] = 0.0f;
  for (int i = tid; i < D * H; i += BLOCK) (&fcw_s[0][0])[i] = fc_w[i];

  // W_hh rows u (reset), u+H (update), u+2H (new) -> registers, float4 loads
  float4 wr[12], wz[12], wn[12];
#pragma unroll
  for (int j = 0; j < 12; ++j) {
    wr[j] = *(const float4*)(W_hh + (u) * H + 4 * j);
    wz[j] = *(const float4*)(W_hh + (u + H) * H + 4 * j);
    wn[j] = *(const float4*)(W_hh + (u + 2 * H) * H + 4 * j);
  }
  float wir[D], wiz[D], win_[D];
#pragma unroll
  for (int d = 0; d < D; ++d) {
    wir[d]  = W_ih[(u) * D + d];
    wiz[d]  = W_ih[(u + H) * D + d];
    win_[d] = W_ih[(u + 2 * H) * D + d];
  }
  const float bir = b_ih[u], biz = b_ih[u + H], bin_ = b_ih[u + 2 * H];
  const float bhr = b_hh[u], bhz = b_hh[u + H], bhn = b_hh[u + 2 * H];

  // FC-phase mapping: 192 threads = 4 batches x 8 timesteps x 6 outputs
  const int yb  = tid / H;
  const int yts = (tid - yb * H) / D;
  const int yd  = tid - yb * H - yts * D;
  const float fcbd = fc_b[yd];

  const float* xp = x + ((size_t)blockIdx.x * NB + bl) * (size_t)T * D;
  float* yp = y + ((size_t)blockIdx.x * NB + yb) * (size_t)T * D;

  __syncthreads();

  float hreg = 0.0f;
  // x[t=0], 8B-aligned float2 loads (rows are 24B)
  float2 xc0 = *(const float2*)(xp + 0);
  float2 xc1 = *(const float2*)(xp + 2);
  float2 xc2 = *(const float2*)(xp + 4);

  for (int t0 = 0; t0 < T; t0 += W) {
#pragma unroll
    for (int tw = 0; tw < W; ++tw) {
      const int t = t0 + tw;
      const int p = (tw + W - 1) & (W - 1);  // read slot (prev h)
      // prefetch x[t+1] before the FMA block (hides global latency)
      const int tn = (t + 1 < T) ? (t + 1) : t;
      const float2 xn0 = *(const float2*)(xp + tn * D + 0);
      const float2 xn1 = *(const float2*)(xp + tn * D + 2);
      const float2 xn2 = *(const float2*)(xp + tn * D + 4);

      float ghr = bhr, ghz = bhz, ghn = bhn;
      const float4* hv4 = (const float4*)(&h_hist[p][bl][0]);
#pragma unroll
      for (int j = 0; j < 12; ++j) {
        const float4 hv = hv4[j];   // broadcast across the 48 lanes of batch bl
        ghr = fmaf(wr[j].x, hv.x, ghr);
        ghz = fmaf(wz[j].x, hv.x, ghz);
        ghn = fmaf(wn[j].x, hv.x, ghn);
        ghr = fmaf(wr[j].y, hv.y, ghr);
        ghz = fmaf(wz[j].y, hv.y, ghz);
        ghn = fmaf(wn[j].y, hv.y, ghn);
        ghr = fmaf(wr[j].z, hv.z, ghr);
        ghz = fmaf(wz[j].z, hv.z, ghz);
        ghn = fmaf(wn[j].z, hv.z, ghn);
        ghr = fmaf(wr[j].w, hv.w, ghr);
        ghz = fmaf(wz[j].w, hv.w, ghz);
        ghn = fmaf(wn[j].w, hv.w, ghn);
      }
      // fused input projection gi = W_ih x + b_ih (D=6)
      float gir = bir, giz = biz, gin = bin_;
      gir = fmaf(wir[0], xc0.x, gir); gir = fmaf(wir[1], xc0.y, gir);
      gir = fmaf(wir[2], xc1.x, gir); gir = fmaf(wir[3], xc1.y, gir);
      gir = fmaf(wir[4], xc2.x, gir); gir = fmaf(wir[5], xc2.y, gir);
      giz = fmaf(wiz[0], xc0.x, giz); giz = fmaf(wiz[1], xc0.y, giz);
      giz = fmaf(wiz[2], xc1.x, giz); giz = fmaf(wiz[3], xc1.y, giz);
      giz = fmaf(wiz[4], xc2.x, giz); giz = fmaf(wiz[5], xc2.y, giz);
      gin = fmaf(win_[0], xc0.x, gin); gin = fmaf(win_[1], xc0.y, gin);
      gin = fmaf(win_[2], xc1.x, gin); gin = fmaf(win_[3], xc1.y, gin);
      gin = fmaf(win_[4], xc2.x, gin); gin = fmaf(win_[5], xc2.y, gin);

      const float r = sigmoid_f(gir + ghr);
      const float z = sigmoid_f(giz + ghz);
      const float n = tanh_f(gin + r * ghn);  // r multiplies gh_n only (incl. b_hh_n)
      hreg = (1.0f - z) * n + z * hreg;
      h_hist[tw][bl][u] = hreg;
      xc0 = xn0; xc1 = xn1; xc2 = xn2;
      __syncthreads();
    }

    // fused FC over the last W steps: one output element per thread
    float acc = fcbd;
    const float4* hv4 = (const float4*)(&h_hist[yts][yb][0]);
    const float4* fw4 = (const float4*)(&fcw_s[yd][0]);
#pragma unroll
    for (int j = 0; j < 12; ++j) {
      const float4 hv = hv4[j];
      const float4 fw = fw4[j];
      acc = fmaf(fw.x, hv.x, acc);
      acc = fmaf(fw.y, hv.y, acc);
      acc = fmaf(fw.z, hv.z, acc);
      acc = fmaf(fw.w, hv.w, acc);
    }
    yp[(t0 + yts) * D + yd] = acc;
    __syncthreads();  // protect h_hist slot 0 from next window's overwrite
  }
}

}  // namespace

extern "C" void kernel_launch(void* const* d_in, const int* in_sizes, int n_in,
                              void* d_out, int out_size, void* d_ws, size_t ws_size,
                              hipStream_t stream) {
  const float* x    = (const float*)d_in[0];
  const float* W_ih = (const float*)d_in[1];
  const float* W_hh = (const float*)d_in[2];
  const float* b_ih = (const float*)d_in[3];
  const float* b_hh = (const float*)d_in[4];
  const float* fc_w = (const float*)d_in[5];
  const float* fc_b = (const float*)d_in[6];
  float* y = (float*)d_out;

  constexpr int B = 2048;
  gru_fused<<<B / NB, BLOCK, 0, stream>>>(x, W_ih, W_hh, b_ih, b_hh, fc_w, fc_b, y);
}